// Round 13
// baseline (1646.651 us; speedup 1.0000x reference)
//
#include <hip/hip_runtime.h>
#include <math.h>
#include <stdint.h>

// Problem constants (from reference setup_inputs)
constexpr int SEQ   = 2048;  // T
constexpr int BATCH = 64;    // B
constexpr int EMB   = 100;   // E
constexpr int HID   = 128;   // H
constexpr int G3    = 384;   // 3*H
constexpr int NS    = 6;     // S (CRF states)
constexpr int BSEL  = 63;    // only batch row 63 affects the output
constexpr int WIN   = 16;    // k_recur window (steps per gi/out staging)
constexpr int NW    = SEQ / WIN;

typedef _Float16 f16x2 __attribute__((ext_vector_type(2)));
typedef _Float16 f16x8 __attribute__((ext_vector_type(8)));
typedef float    f32x4 __attribute__((ext_vector_type(4)));

union U16x8 { uint4 u; f16x8 h; };

__device__ __forceinline__ uint32_t pack_f16(float a, float b) {
    f16x2 p; p.x = (_Float16)a; p.y = (_Float16)b;
    return __builtin_bit_cast(uint32_t, p);
}
__device__ __forceinline__ float half_sel(uint32_t p, int hi) {
    const f16x2 v = __builtin_bit_cast(f16x2, p);
    return hi ? (float)v.y : (float)v.x;
}

// ---------------------------------------------------------------------------
// Kernel 1: embedding lookup + input projection for batch row 63 only.
// 16 t/block; emits gi transposed as packed f16 unit-pairs:
//   gi_t[(g*64+u2)*SEQ + t]   (R8-proven layout, unchanged)
// ---------------------------------------------------------------------------
__global__ __launch_bounds__(G3) void k_input_proj(
    const int* __restrict__ sent, const float* __restrict__ emb,
    const float* __restrict__ Wf_ih, const float* __restrict__ bf_ih,
    const float* __restrict__ Wb_ih, const float* __restrict__ bb_ih,
    uint32_t* __restrict__ gi_ft, uint32_t* __restrict__ gi_bt)
{
    const int tb = blockIdx.x * 16;
    const int j  = threadIdx.x;           // 0..383 = weight row (g*128 + u)
    __shared__ __align__(16) float x_s[16][EMB];

    if (j < EMB) {
        for (int tt = 0; tt < 16; ++tt) {
            const int tok = sent[BSEL * SEQ + tb + tt];
            x_s[tt][j] = emb[(size_t)tok * EMB + j];
        }
    }
    __syncthreads();

    float4 wf4[25], wb4[25];
    const float4* wfp = (const float4*)(Wf_ih + (size_t)j * EMB);
    const float4* wbp = (const float4*)(Wb_ih + (size_t)j * EMB);
#pragma unroll
    for (int m = 0; m < 25; ++m) { wf4[m] = wfp[m]; wb4[m] = wbp[m]; }
    const float bf = bf_ih[j], bb = bb_ih[j];

    const int g  = j >> 7;
    const int u  = j & 127;
    const int u2 = u >> 1;
    const size_t orow = ((size_t)(g * 64 + u2)) * SEQ;

    for (int tt = 0; tt < 16; ++tt) {
        const float4* xs = (const float4*)(x_s[tt]);
        float af = 0.f, ab = 0.f;
#pragma unroll
        for (int m = 0; m < 25; ++m) {
            const float4 xv = xs[m];
            af = fmaf(wf4[m].x, xv.x, af); af = fmaf(wf4[m].y, xv.y, af);
            af = fmaf(wf4[m].z, xv.z, af); af = fmaf(wf4[m].w, xv.w, af);
            ab = fmaf(wb4[m].x, xv.x, ab); ab = fmaf(wb4[m].y, xv.y, ab);
            ab = fmaf(wb4[m].z, xv.z, ab); ab = fmaf(wb4[m].w, xv.w, ab);
        }
        const float vf = af + bf;
        const float vb = ab + bb;
        const float vf_n = __shfl_xor(vf, 1);
        const float vb_n = __shfl_xor(vb, 1);
        if ((u & 1) == 0) {
            gi_ft[orow + tb + tt] = pack_f16(vf, vf_n);
            gi_bt[orow + tb + tt] = pack_f16(vb, vb_n);
        }
    }
}

// ---------------------------------------------------------------------------
// Kernel 2: GRU recurrence on the MATRIX pipe. 512 thr/block, one per dir.
// Wave w owns units [16w,16w+16). Per step: 12 mfma_f32_16x16x32_f16
// (3 gates x 4 K-tiles); A = Whh fragments (lane m=lane&15, k=32kt+8q+j,
// q=lane>>4 — verified mapping); B = h broadcast across n (4 ds_read_b128).
// D row = 4q+r -> lane's 4 gate-units; gates redundant across the 16
// n-lanes; n==0 writes h (f16 pairs) + out_lds.
// gi bulk-staged to LDS once per 16-step window (coalesced; one drain per
// window — R12's amortization); outputs dumped once per window.
// ---------------------------------------------------------------------------
template <int DIR>
__device__ void gru_run(const uint32_t* __restrict__ git,
                        const float* __restrict__ Whh,
                        const float* __restrict__ bhh,
                        const float* __restrict__ h0,
                        float* __restrict__ outs)
{
    const int tid  = threadIdx.x;
    const int lane = tid & 63;
    const int wv   = tid >> 6;            // 0..7
    const int q    = lane >> 4;           // 0..3
    const int n    = lane & 15;           // 0..15
    const int u4   = 16 * wv + 4 * q;     // this lane's 4 gate units

    // A fragments: 3 gates x 4 K-tiles, f16
    f16x8 Af[3][4];
#pragma unroll
    for (int g = 0; g < 3; ++g) {
        const float* wrow = Whh + (size_t)(g * HID + 16 * wv + n) * HID;
#pragma unroll
        for (int kt = 0; kt < 4; ++kt) {
            const float* p8 = wrow + 32 * kt + 8 * q;
            f16x8 a;
#pragma unroll
            for (int jj = 0; jj < 8; ++jj) a[jj] = (_Float16)p8[jj];
            Af[g][kt] = a;
        }
    }

    const f32x4 b_r4 = *(const f32x4*)(bhh + u4);
    const f32x4 b_z4 = *(const f32x4*)(bhh + HID + u4);
    const f32x4 b_n4 = *(const f32x4*)(bhh + 2 * HID + u4);

    f32x4 hq = *(const f32x4*)(h0 + (size_t)DIR * BATCH * HID + BSEL * HID + u4);

    __shared__ __align__(16) uint32_t h_lds[2][HID / 2];
    __shared__ __align__(16) uint32_t gi_lds[2][WIN][3][64];   // 24.5 KB
    __shared__ __align__(16) float    out_lds[WIN][HID];       // 8 KB

    if (tid < HID / 2) {
        const float2 hh = *(const float2*)(h0 + (size_t)DIR * BATCH * HID + BSEL * HID + 2 * tid);
        h_lds[0][tid] = pack_f16(hh.x, hh.y);
    }

    // staging map: idx = tid + i*512; s = idx&15 (==tid&15), r = idx>>4,
    // g = r>>6, u2 = r&63. Global read (g*64+u2)*SEQ + (t0 +/- s) is
    // 16-consecutive-t per 16-lane group -> coalesced 64B segments.
    const int st_s = tid & 15;
    uint32_t gcu[6];
    {
        const int t00 = DIR ? (SEQ - 1) : 0;
        const int t   = DIR ? (t00 - st_s) : (t00 + st_s);
#pragma unroll
        for (int i = 0; i < 6; ++i) {
            const int r  = (tid >> 4) + i * 32;
            const int g  = r >> 6, u2 = r & 63;
            gcu[i] = git[(size_t)(g * 64 + u2) * SEQ + t];
        }
#pragma unroll
        for (int i = 0; i < 6; ++i) {
            const int r = (tid >> 4) + i * 32;
            gi_lds[0][st_s][r >> 6][r & 63] = gcu[i];
        }
    }
    __syncthreads();

    const f32x4 z4 = {0.f, 0.f, 0.f, 0.f};

#define GRU_STEP(S, BUF) do {                                                  \
    const int cur = (S) & 1;                                                   \
    const uint4* hb = (const uint4*)(h_lds[cur]);                              \
    U16x8 B0, B1, B2, B3;                                                      \
    B0.u = hb[q]; B1.u = hb[q + 4]; B2.u = hb[q + 8]; B3.u = hb[q + 12];       \
    const uint2 gi_r = *(const uint2*)&gi_lds[BUF][S][0][u4 >> 1];             \
    const uint2 gi_z = *(const uint2*)&gi_lds[BUF][S][1][u4 >> 1];             \
    const uint2 gi_n = *(const uint2*)&gi_lds[BUF][S][2][u4 >> 1];             \
    f32x4 aR = __builtin_amdgcn_mfma_f32_16x16x32_f16(Af[0][0], B0.h, z4, 0, 0, 0); \
    f32x4 aZ = __builtin_amdgcn_mfma_f32_16x16x32_f16(Af[1][0], B0.h, z4, 0, 0, 0); \
    f32x4 aN = __builtin_amdgcn_mfma_f32_16x16x32_f16(Af[2][0], B0.h, z4, 0, 0, 0); \
    aR = __builtin_amdgcn_mfma_f32_16x16x32_f16(Af[0][1], B1.h, aR, 0, 0, 0);  \
    aZ = __builtin_amdgcn_mfma_f32_16x16x32_f16(Af[1][1], B1.h, aZ, 0, 0, 0);  \
    aN = __builtin_amdgcn_mfma_f32_16x16x32_f16(Af[2][1], B1.h, aN, 0, 0, 0);  \
    aR = __builtin_amdgcn_mfma_f32_16x16x32_f16(Af[0][2], B2.h, aR, 0, 0, 0);  \
    aZ = __builtin_amdgcn_mfma_f32_16x16x32_f16(Af[1][2], B2.h, aZ, 0, 0, 0);  \
    aN = __builtin_amdgcn_mfma_f32_16x16x32_f16(Af[2][2], B2.h, aN, 0, 0, 0);  \
    aR = __builtin_amdgcn_mfma_f32_16x16x32_f16(Af[0][3], B3.h, aR, 0, 0, 0);  \
    aZ = __builtin_amdgcn_mfma_f32_16x16x32_f16(Af[1][3], B3.h, aZ, 0, 0, 0);  \
    aN = __builtin_amdgcn_mfma_f32_16x16x32_f16(Af[2][3], B3.h, aN, 0, 0, 0);  \
    const float gir[4] = {half_sel(gi_r.x, 0), half_sel(gi_r.x, 1),            \
                          half_sel(gi_r.y, 0), half_sel(gi_r.y, 1)};           \
    const float giz[4] = {half_sel(gi_z.x, 0), half_sel(gi_z.x, 1),            \
                          half_sel(gi_z.y, 0), half_sel(gi_z.y, 1)};           \
    const float gin[4] = {half_sel(gi_n.x, 0), half_sel(gi_n.x, 1),            \
                          half_sel(gi_n.y, 0), half_sel(gi_n.y, 1)};           \
    _Pragma("unroll")                                                          \
    for (int r = 0; r < 4; ++r) {                                              \
        const float rg = __builtin_amdgcn_rcpf(1.f + __expf(-(gir[r] + b_r4[r] + aR[r]))); \
        const float zg = __builtin_amdgcn_rcpf(1.f + __expf(-(giz[r] + b_z4[r] + aZ[r]))); \
        float ttv = gin[r] + rg * (aN[r] + b_n4[r]);                           \
        ttv = fminf(fmaxf(ttv, -15.f), 15.f);                                  \
        const float e  = __expf(-2.f * ttv);                                   \
        const float ng = fmaf(2.f, __builtin_amdgcn_rcpf(1.f + e), -1.f);      \
        hq[r] = (1.f - zg) * ng + zg * hq[r];                                  \
    }                                                                          \
    if (n == 0) {                                                              \
        uint2 w2; w2.x = pack_f16(hq[0], hq[1]); w2.y = pack_f16(hq[2], hq[3]);\
        *(uint2*)&h_lds[cur ^ 1][u4 >> 1] = w2;                                \
        *(float4*)&out_lds[S][u4] = float4{hq[0], hq[1], hq[2], hq[3]};        \
    }                                                                          \
    __syncthreads();                                                           \
} while (0)

    for (int w = 0; w < NW; ++w) {
        const int buf = w & 1;
        GRU_STEP(0, buf);  GRU_STEP(1, buf);  GRU_STEP(2, buf);  GRU_STEP(3, buf);
        GRU_STEP(4, buf);  GRU_STEP(5, buf);  GRU_STEP(6, buf);  GRU_STEP(7, buf);
        GRU_STEP(8, buf);  GRU_STEP(9, buf);  GRU_STEP(10, buf); GRU_STEP(11, buf);
        GRU_STEP(12, buf); GRU_STEP(13, buf); GRU_STEP(14, buf); GRU_STEP(15, buf);

        // ---- window end: dump outputs (reads ordered by step-15 barrier) ----
        {
            const int idx = tid * 4;
            const int s = idx >> 7, u = idx & 127;
            const int tg = DIR ? (SEQ - 1 - WIN * w - s) : (WIN * w + s);
            *(float4*)(outs + (size_t)tg * HID + u) = *(const float4*)&out_lds[s][u];
        }
        // ---- stage next window's gi ----
        if (w + 1 < NW) {
            const int t0n = DIR ? (SEQ - 1 - WIN * (w + 1)) : (WIN * (w + 1));
            const int t   = DIR ? (t0n - st_s) : (t0n + st_s);
#pragma unroll
            for (int i = 0; i < 6; ++i) {
                const int r  = (tid >> 4) + i * 32;
                const int g  = r >> 6, u2 = r & 63;
                gcu[i] = git[(size_t)(g * 64 + u2) * SEQ + t];
            }
#pragma unroll
            for (int i = 0; i < 6; ++i) {
                const int r = (tid >> 4) + i * 32;
                gi_lds[buf ^ 1][st_s][r >> 6][r & 63] = gcu[i];
            }
        }
        __syncthreads();   // orders gi writes for next window; drains stores
    }
#undef GRU_STEP
}

__global__ __launch_bounds__(512, 1) void k_recur(
    const uint32_t* __restrict__ gi_ft, const uint32_t* __restrict__ gi_bt,
    const float* __restrict__ Wf_hh, const float* __restrict__ bf_hh,
    const float* __restrict__ Wb_hh, const float* __restrict__ bb_hh,
    const float* __restrict__ h0,
    float* __restrict__ fwd, float* __restrict__ bwd)
{
    if (blockIdx.x == 0) gru_run<0>(gi_ft, Wf_hh, bf_hh, h0, fwd);
    else                 gru_run<1>(gi_bt, Wb_hh, bb_hh, h0, bwd);
}

// ---------------------------------------------------------------------------
// Kernel 3a: logits + softmax, PARALLEL over t (R10-verified, unchanged)
// ---------------------------------------------------------------------------
__global__ __launch_bounds__(256) void k_logits(
    const float* __restrict__ fwd, const float* __restrict__ bwd,
    const float* __restrict__ W_out, const float* __restrict__ b_out,
    float* __restrict__ probs)
{
    __shared__ __align__(16) float4 Wl[NS][64];
    __shared__ float bl[NS];

    const int tid = threadIdx.x;
    for (int i = tid; i < NS * 64; i += 256)
        Wl[i >> 6][i & 63] = ((const float4*)W_out)[i];
    if (tid < NS) bl[tid] = b_out[tid];
    __syncthreads();

    const int t = blockIdx.x * 256 + tid;
    const float4* f4 = (const float4*)(fwd + (size_t)t * HID);
    const float4* b4 = (const float4*)(bwd + (size_t)t * HID);
    float lg[NS];
#pragma unroll
    for (int s = 0; s < NS; ++s) lg[s] = bl[s];
#pragma unroll 4
    for (int k4 = 0; k4 < 32; ++k4) {
        const float4 fv = f4[k4];
        const float4 bv = b4[k4];
#pragma unroll
        for (int s = 0; s < NS; ++s) {
            const float4 wf = Wl[s][k4];
            const float4 wb = Wl[s][k4 + 32];
            lg[s] += wf.x * fv.x + wf.y * fv.y + wf.z * fv.z + wf.w * fv.w
                   + wb.x * bv.x + wb.y * bv.y + wb.z * bv.z + wb.w * bv.w;
        }
    }
    float m = lg[0];
#pragma unroll
    for (int s = 1; s < NS; ++s) m = fmaxf(m, lg[s]);
    float sum = 0.f;
#pragma unroll
    for (int s = 0; s < NS; ++s) { lg[s] = __expf(lg[s] - m); sum += lg[s]; }
    const float inv = 1.f / sum;
    float* po = probs + (size_t)t * NS;
    *(float2*)(po)     = float2{lg[0] * inv, lg[1] * inv};
    *(float2*)(po + 2) = float2{lg[2] * inv, lg[3] * inv};
    *(float2*)(po + 4) = float2{lg[4] * inv, lg[5] * inv};
}

// ---------------------------------------------------------------------------
// Kernel 3b: PARALLEL Viterbi via (max,+) segmented scan (R10-verified)
// ---------------------------------------------------------------------------
__global__ __launch_bounds__(G3) void k_viterbi(
    const float* __restrict__ probs, const float* __restrict__ trans,
    float* __restrict__ out)
{
    __shared__ float p_lds[SEQ * NS];
    __shared__ uint32_t bp32[SEQ - 1];
    __shared__ float Pmat[32][NS][NS];
    __shared__ float vstart[32][NS];
    __shared__ unsigned char cmap[32 * NS];
    __shared__ int bstate[32];
    __shared__ int s_last;

    const int tid = threadIdx.x;

    {
        const float4* src = (const float4*)probs;
        float4* dst = (float4*)p_lds;
#pragma unroll
        for (int r = 0; r < 8; ++r) dst[tid + r * G3] = src[tid + r * G3];
    }
    __syncthreads();

    if (tid < 32 * NS) {
        const int c = tid / NS, i = tid % NS;
        float tc[NS][NS];
#pragma unroll
        for (int k = 0; k < NS; ++k)
#pragma unroll
            for (int j = 0; j < NS; ++j) tc[k][j] = trans[k * NS + j];
        float R[NS];
#pragma unroll
        for (int j = 0; j < NS; ++j) R[j] = (j == i) ? 0.f : -3.0e38f;
        const int lo = 64 * c;
        const int hi = (c == 31) ? (SEQ - 1) : 64 * (c + 1);
        for (int tau = lo + 1; tau <= hi; ++tau) {
            const float2 p01 = *(const float2*)&p_lds[tau * NS];
            const float2 p23 = *(const float2*)&p_lds[tau * NS + 2];
            const float2 p45 = *(const float2*)&p_lds[tau * NS + 4];
            const float pj[NS] = {p01.x, p01.y, p23.x, p23.y, p45.x, p45.y};
            float Rn[NS];
#pragma unroll
            for (int j = 0; j < NS; ++j) {
                float mx = R[0] + tc[0][j];
                mx = fmaxf(mx, R[1] + tc[1][j]);
                mx = fmaxf(mx, R[2] + tc[2][j]);
                mx = fmaxf(mx, R[3] + tc[3][j]);
                mx = fmaxf(mx, R[4] + tc[4][j]);
                mx = fmaxf(mx, R[5] + tc[5][j]);
                Rn[j] = mx + pj[j];
            }
#pragma unroll
            for (int j = 0; j < NS; ++j) R[j] = Rn[j];
        }
#pragma unroll
        for (int j = 0; j < NS; ++j) Pmat[c][i][j] = R[j];
    }
    __syncthreads();

    if (tid == 0) {
        float v[NS];
#pragma unroll
        for (int j = 0; j < NS; ++j) { v[j] = p_lds[j]; vstart[0][j] = v[j]; }
        for (int c = 0; c < 31; ++c) {
            float vn[NS];
#pragma unroll
            for (int j = 0; j < NS; ++j) {
                float mx = v[0] + Pmat[c][0][j];
                mx = fmaxf(mx, v[1] + Pmat[c][1][j]);
                mx = fmaxf(mx, v[2] + Pmat[c][2][j]);
                mx = fmaxf(mx, v[3] + Pmat[c][3][j]);
                mx = fmaxf(mx, v[4] + Pmat[c][4][j]);
                mx = fmaxf(mx, v[5] + Pmat[c][5][j]);
                vn[j] = mx;
            }
#pragma unroll
            for (int j = 0; j < NS; ++j) { v[j] = vn[j]; vstart[c + 1][j] = vn[j]; }
        }
    }
    __syncthreads();

    if (tid < 32) {
        const int c = tid;
        float tc[NS][NS];
#pragma unroll
        for (int k = 0; k < NS; ++k)
#pragma unroll
            for (int j = 0; j < NS; ++j) tc[k][j] = trans[k * NS + j];
        float v[NS];
#pragma unroll
        for (int j = 0; j < NS; ++j) v[j] = vstart[c][j];
        const int lo = 64 * c;
        const int hi = (c == 31) ? (SEQ - 1) : 64 * (c + 1);
        for (int tau = lo + 1; tau <= hi; ++tau) {
            const float2 p01 = *(const float2*)&p_lds[tau * NS];
            const float2 p23 = *(const float2*)&p_lds[tau * NS + 2];
            const float2 p45 = *(const float2*)&p_lds[tau * NS + 4];
            const float pj[NS] = {p01.x, p01.y, p23.x, p23.y, p45.x, p45.y};
            uint32_t bpw = 0;
            float vn[NS];
#pragma unroll
            for (int j = 0; j < NS; ++j) {
                const float c0 = v[0] + tc[0][j];
                const float c1 = v[1] + tc[1][j];
                const float c2 = v[2] + tc[2][j];
                const float c3 = v[3] + tc[3][j];
                const float c4 = v[4] + tc[4][j];
                const float c5 = v[5] + tc[5][j];
                const float best = fmaxf(fmaxf(fmaxf(c0, c1), c2),
                                         fmaxf(fmaxf(c3, c4), c5));
                int bi = 5;
                bi = (c4 == best) ? 4 : bi;
                bi = (c3 == best) ? 3 : bi;
                bi = (c2 == best) ? 2 : bi;
                bi = (c1 == best) ? 1 : bi;
                bi = (c0 == best) ? 0 : bi;
                bpw |= ((uint32_t)bi) << (3 * j);
                vn[j] = pj[j] + best;
            }
            bp32[tau - 1] = bpw;
#pragma unroll
            for (int j = 0; j < NS; ++j) v[j] = vn[j];
        }
        if (c == 31) {
            const float best = fmaxf(fmaxf(fmaxf(v[0], v[1]), v[2]),
                                     fmaxf(fmaxf(v[3], v[4]), v[5]));
            int bi = 5;
            bi = (v[4] == best) ? 4 : bi;
            bi = (v[3] == best) ? 3 : bi;
            bi = (v[2] == best) ? 2 : bi;
            bi = (v[1] == best) ? 1 : bi;
            bi = (v[0] == best) ? 0 : bi;
            out[0] = best; s_last = bi;
        }
    }
    __syncthreads();

    if (tid < 32 * NS) {
        const int c = tid / NS, s0 = tid % NS;
        const int hi = (c == 31) ? (SEQ - 1) : 64 * (c + 1);
        const int lo = 64 * c;
        int s = s0;
        for (int tau = hi; tau > lo; --tau)
            s = (bp32[tau - 1] >> (3 * s)) & 7;
        cmap[c * NS + s0] = (unsigned char)s;
    }
    __syncthreads();

    if (tid == 0) {
        int s = s_last;
        for (int c = 31; c >= 0; --c) {
            s = cmap[c * NS + s];
            bstate[c] = s;
        }
    }
    __syncthreads();

    if (tid < 32) {
        const int c = tid;
        const int hi = (c == 31) ? (SEQ - 1) : 64 * (c + 1);
        const int lo = 64 * c;
        int s = (c == 31) ? s_last : bstate[c + 1];
        for (int tau = hi; tau > lo; --tau) {
            out[1 + tau] = (float)s;
            s = (bp32[tau - 1] >> (3 * s)) & 7;
        }
        if (c == 0) out[1] = (float)s;   // time 0
    }
}

// ---------------------------------------------------------------------------
extern "C" void kernel_launch(void* const* d_in, const int* in_sizes, int n_in,
                              void* d_out, int out_size, void* d_ws, size_t ws_size,
                              hipStream_t stream)
{
    (void)in_sizes; (void)n_in; (void)out_size; (void)ws_size;

    const int*   sent  = (const int*)  d_in[0];
    const float* emb   = (const float*)d_in[1];
    const float* h0    = (const float*)d_in[2];
    const float* Wf_ih = (const float*)d_in[3];
    const float* Wf_hh = (const float*)d_in[4];
    const float* bf_ih = (const float*)d_in[5];
    const float* bf_hh = (const float*)d_in[6];
    const float* Wb_ih = (const float*)d_in[7];
    const float* Wb_hh = (const float*)d_in[8];
    const float* bb_ih = (const float*)d_in[9];
    const float* bb_hh = (const float*)d_in[10];
    const float* W_out = (const float*)d_in[11];
    const float* b_out = (const float*)d_in[12];
    const float* trans = (const float*)d_in[13];
    float* out = (float*)d_out;

    // workspace layout (floats): gi_ft | gi_bt | fwd | bwd.
    // probs aliases gi_ft (dead after k_recur).
    float*    ws    = (float*)d_ws;
    uint32_t* gi_ft = (uint32_t*)ws;
    uint32_t* gi_bt = gi_ft + (size_t)SEQ * 192;
    float*    fwdb  = ws + (size_t)2 * SEQ * G3;
    float*    bwdb  = fwdb + (size_t)SEQ * HID;
    float*    probs = ws;                     // alias of gi_ft region

    k_input_proj<<<SEQ / 16, G3, 0, stream>>>(sent, emb, Wf_ih, bf_ih, Wb_ih, bb_ih, gi_ft, gi_bt);
    k_recur<<<2, 512, 0, stream>>>(gi_ft, gi_bt, Wf_hh, bf_hh, Wb_hh, bb_hh, h0, fwdb, bwdb);
    k_logits<<<SEQ / 256, 256, 0, stream>>>(fwdb, bwdb, W_out, b_out, probs);
    k_viterbi<<<1, G3, 0, stream>>>(probs, trans, out);
}

// Round 14
// 1048.139 us; speedup vs baseline: 1.5710x; 1.5710x over previous
//
#include <hip/hip_runtime.h>
#include <math.h>
#include <stdint.h>

// Problem constants (from reference setup_inputs)
constexpr int SEQ   = 2048;  // T
constexpr int BATCH = 64;    // B
constexpr int EMB   = 100;   // E
constexpr int HID   = 128;   // H
constexpr int G3    = 384;   // 3*H
constexpr int NS    = 6;     // S (CRF states)
constexpr int BSEL  = 63;    // only batch row 63 affects the output

#define KEEPI(v) asm volatile("" : "+v"(v))

typedef _Float16 f16x2 __attribute__((ext_vector_type(2)));

__device__ __forceinline__ f16x2 u2h(uint32_t x) {
    return __builtin_bit_cast(f16x2, x);
}
__device__ __forceinline__ uint32_t pack_f16(float a, float b) {
    f16x2 p; p.x = (_Float16)a; p.y = (_Float16)b;
    return __builtin_bit_cast(uint32_t, p);
}
__device__ __forceinline__ float half_sel(uint32_t p, int hi) {
    const f16x2 v = __builtin_bit_cast(f16x2, p);
    return hi ? (float)v.y : (float)v.x;
}

template <int CTRL>
__device__ __forceinline__ float dpp_add(float x) {
    int v = __builtin_amdgcn_update_dpp(0, __float_as_int(x), CTRL, 0xF, 0xF, true);
    return x + __int_as_float(v);
}
template <int CTRL>
__device__ __forceinline__ uint32_t dpp_bcast(uint32_t x) {
    return (uint32_t)__builtin_amdgcn_update_dpp(0, (int)x, CTRL, 0xF, 0xF, true);
}

// ---------------------------------------------------------------------------
// Kernel 1: embedding lookup + input projection for batch row 63 only.
// 16 timesteps per block; emits gi TRANSPOSED as packed f16 unit-pairs
// (R12-proven, unchanged).
// ---------------------------------------------------------------------------
__global__ __launch_bounds__(G3) void k_input_proj(
    const int* __restrict__ sent, const float* __restrict__ emb,
    const float* __restrict__ Wf_ih, const float* __restrict__ bf_ih,
    const float* __restrict__ Wb_ih, const float* __restrict__ bb_ih,
    uint32_t* __restrict__ gi_ft, uint32_t* __restrict__ gi_bt)
{
    const int tb = blockIdx.x * 16;
    const int j  = threadIdx.x;           // 0..383 = weight row (g*128 + u)
    __shared__ __align__(16) float x_s[16][EMB];

    if (j < EMB) {
        for (int tt = 0; tt < 16; ++tt) {
            const int tok = sent[BSEL * SEQ + tb + tt];
            x_s[tt][j] = emb[(size_t)tok * EMB + j];
        }
    }
    __syncthreads();

    float4 wf4[25], wb4[25];
    const float4* wfp = (const float4*)(Wf_ih + (size_t)j * EMB);
    const float4* wbp = (const float4*)(Wb_ih + (size_t)j * EMB);
#pragma unroll
    for (int m = 0; m < 25; ++m) { wf4[m] = wfp[m]; wb4[m] = wbp[m]; }
    const float bf = bf_ih[j], bb = bb_ih[j];

    const int g  = j >> 7;
    const int u  = j & 127;
    const int u2 = u >> 1;
    const size_t orow = ((size_t)(g * 64 + u2)) * SEQ;

    for (int tt = 0; tt < 16; ++tt) {
        const float4* xs = (const float4*)(x_s[tt]);
        float af = 0.f, ab = 0.f;
#pragma unroll
        for (int m = 0; m < 25; ++m) {
            const float4 xv = xs[m];
            af = fmaf(wf4[m].x, xv.x, af); af = fmaf(wf4[m].y, xv.y, af);
            af = fmaf(wf4[m].z, xv.z, af); af = fmaf(wf4[m].w, xv.w, af);
            ab = fmaf(wb4[m].x, xv.x, ab); ab = fmaf(wb4[m].y, xv.y, ab);
            ab = fmaf(wb4[m].z, xv.z, ab); ab = fmaf(wb4[m].w, xv.w, ab);
        }
        const float vf = af + bf;
        const float vb = ab + bb;
        const float vf_n = __shfl_xor(vf, 1);
        const float vb_n = __shfl_xor(vb, 1);
        if ((u & 1) == 0) {
            gi_ft[orow + tb + tt] = pack_f16(vf, vf_n);
            gi_bt[orow + tb + tt] = pack_f16(vb, vb_n);
        }
    }
}

// ---------------------------------------------------------------------------
// Kernel 2: GRU recurrence — R12 structure (256 thr/block, 1 wave/SIMD,
// one block per direction, weights resident in VGPRs, gi per-16-step
// window, outputs buffered per window), with the matvec on
// v_pk_fma_f16 (full-rate, 2 MACs/instr) instead of v_dot2_f32_f16
// (half-rate — R12's VALUBusy fit: 96 dot2 x 4 cyc = 384 of 580 busy
// cyc/step). Accumulate in f16x2, two interleaved chains per gate for
// ILP; horizontal add + DPP pair-reduce in f32.
// Thread = (unit u = tid>>1, half = tid&1 -> 64-col slice).
// ---------------------------------------------------------------------------
template <int DIR>
__device__ void gru_run(const uint32_t* __restrict__ git,
                        const float* __restrict__ Whh,
                        const float* __restrict__ bhh,
                        const float* __restrict__ h0,
                        float* __restrict__ outs)
{
    const int tid  = threadIdx.x;         // 0..255
    const int u    = tid >> 1;            // unit 0..127
    const int half = tid & 1;             // 64-col slice
    const int u2   = u >> 1;              // quad index
    const int kq   = tid & 3;             // lane-in-quad
    const int halfu = u & 1;              // which half of the u2 pack

    // --- weights: rows {u, 128+u, 256+u}, cols [64*half, 64*half+64), f16
    uint32_t Wp0[32], Wp1[32], Wp2[32];
    {
        const float* r0 = Whh + (size_t)u * HID + 64 * half;
        const float* r1 = Whh + (size_t)(HID + u) * HID + 64 * half;
        const float* r2 = Whh + (size_t)(2 * HID + u) * HID + 64 * half;
#pragma unroll
        for (int m4 = 0; m4 < 16; ++m4) {
            const float4 a = ((const float4*)r0)[m4];
            const float4 b = ((const float4*)r1)[m4];
            const float4 c = ((const float4*)r2)[m4];
            Wp0[2 * m4] = pack_f16(a.x, a.y); Wp0[2 * m4 + 1] = pack_f16(a.z, a.w);
            Wp1[2 * m4] = pack_f16(b.x, b.y); Wp1[2 * m4 + 1] = pack_f16(b.z, b.w);
            Wp2[2 * m4] = pack_f16(c.x, c.y); Wp2[2 * m4 + 1] = pack_f16(c.z, c.w);
        }
#pragma unroll
        for (int m = 0; m < 32; ++m) { KEEPI(Wp0[m]); KEEPI(Wp1[m]); KEEPI(Wp2[m]); }
    }

    const float b_r = bhh[u];
    const float b_z = bhh[HID + u];
    const float b_n = bhh[2 * HID + u];

    float h_u = h0[(size_t)DIR * BATCH * HID + BSEL * HID + u];

    const uint32_t* grb = git + (size_t)(0 * 64 + u2) * SEQ;
    const uint32_t* gzb = git + (size_t)(1 * 64 + u2) * SEQ;
    const uint32_t* gnb = git + (size_t)(2 * 64 + u2) * SEQ;

    __shared__ __align__(16) uint32_t h_lds[2][HID / 2];
    if (tid < HID / 2) {
        const float2 hh = *(const float2*)(h0 + (size_t)DIR * BATCH * HID + BSEL * HID + 2 * tid);
        h_lds[0][tid] = pack_f16(hh.x, hh.y);
    }

    // window-0 gi: lane kq holds in-window t-slots 4s+kq, s=0..3
    uint32_t gcu[4][3];
    {
        const int bt = DIR ? (SEQ - 16) : 0;
#pragma unroll
        for (int s = 0; s < 4; ++s) {
            gcu[s][0] = grb[bt + 4 * s + kq];
            gcu[s][1] = gzb[bt + 4 * s + kq];
            gcu[s][2] = gnb[bt + 4 * s + kq];
        }
    }
    __syncthreads();   // drains prologue loads once

    float hs0 = 0, hs1 = 0, hs2 = 0, hs3 = 0, hs4 = 0, hs5 = 0, hs6 = 0, hs7 = 0,
          hs8 = 0, hs9 = 0, hs10 = 0, hs11 = 0, hs12 = 0, hs13 = 0, hs14 = 0, hs15 = 0;

// 12 v_pk_fma_f16 on one uint4's components: chains A (x,z) and B (y,w)
// per gate, interleaved for ILP.
#define PKQ(m, q) \
    aA0 = __builtin_elementwise_fma(u2h(Wp0[4*(m)+0]), u2h((q).x), aA0); \
    aA1 = __builtin_elementwise_fma(u2h(Wp1[4*(m)+0]), u2h((q).x), aA1); \
    aA2 = __builtin_elementwise_fma(u2h(Wp2[4*(m)+0]), u2h((q).x), aA2); \
    aB0 = __builtin_elementwise_fma(u2h(Wp0[4*(m)+1]), u2h((q).y), aB0); \
    aB1 = __builtin_elementwise_fma(u2h(Wp1[4*(m)+1]), u2h((q).y), aB1); \
    aB2 = __builtin_elementwise_fma(u2h(Wp2[4*(m)+1]), u2h((q).y), aB2); \
    aA0 = __builtin_elementwise_fma(u2h(Wp0[4*(m)+2]), u2h((q).z), aA0); \
    aA1 = __builtin_elementwise_fma(u2h(Wp1[4*(m)+2]), u2h((q).z), aA1); \
    aA2 = __builtin_elementwise_fma(u2h(Wp2[4*(m)+2]), u2h((q).z), aA2); \
    aB0 = __builtin_elementwise_fma(u2h(Wp0[4*(m)+3]), u2h((q).w), aB0); \
    aB1 = __builtin_elementwise_fma(u2h(Wp1[4*(m)+3]), u2h((q).w), aB1); \
    aB2 = __builtin_elementwise_fma(u2h(Wp2[4*(m)+3]), u2h((q).w), aB2);

#define GRU_STEP(I, KIDX) do {                                                 \
    const uint4* hb4 = (const uint4*)(h_lds[(I) & 1]) + half * 8;              \
    const uint4 q0 = hb4[0], q1 = hb4[1], q2 = hb4[2], q3 = hb4[3];            \
    const uint4 q4 = hb4[4], q5 = hb4[5], q6 = hb4[6], q7 = hb4[7];            \
    f16x2 aA0 = {0, 0}, aA1 = {0, 0}, aA2 = {0, 0};                            \
    f16x2 aB0 = {0, 0}, aB1 = {0, 0}, aB2 = {0, 0};                            \
    PKQ(0, q0) PKQ(1, q1) PKQ(2, q2) PKQ(3, q3)                                \
    PKQ(4, q4) PKQ(5, q5) PKQ(6, q6) PKQ(7, q7)                                \
    const f16x2 sR = aA0 + aB0;                                                \
    const f16x2 sZ = aA1 + aB1;                                                \
    const f16x2 sN = aA2 + aB2;                                                \
    float ar = (float)sR.x + (float)sR.y;                                      \
    float az = (float)sZ.x + (float)sZ.y;                                      \
    float an = (float)sN.x + (float)sN.y;                                      \
    ar = dpp_add<0xB1>(ar);                                                    \
    az = dpp_add<0xB1>(az);                                                    \
    an = dpp_add<0xB1>(an);                                                    \
    const uint32_t gur = dpp_bcast<((KIDX) & 3) * 0x55>(gcu[(KIDX) >> 2][0]);  \
    const uint32_t guz = dpp_bcast<((KIDX) & 3) * 0x55>(gcu[(KIDX) >> 2][1]);  \
    const uint32_t gun = dpp_bcast<((KIDX) & 3) * 0x55>(gcu[(KIDX) >> 2][2]);  \
    const float gr = half_sel(gur, halfu) + b_r;                               \
    const float gz = half_sel(guz, halfu) + b_z;                               \
    const float gn = half_sel(gun, halfu);                                     \
    const float rg = __builtin_amdgcn_rcpf(1.f + __expf(-(gr + ar)));          \
    const float zg = __builtin_amdgcn_rcpf(1.f + __expf(-(gz + az)));          \
    float ttv = gn + rg * (an + b_n);                                          \
    ttv = fminf(fmaxf(ttv, -15.f), 15.f);                                      \
    const float e = __expf(-2.f * ttv);                                        \
    const float ng = fmaf(2.f, __builtin_amdgcn_rcpf(1.f + e), -1.f);          \
    h_u = (1.f - zg) * ng + zg * h_u;                                          \
    if (half == 0) {                                                           \
        hs##I = h_u;                                                           \
        ((_Float16*)(h_lds[((I) & 1) ^ 1]))[u] = (_Float16)h_u;                \
    }                                                                          \
    __syncthreads();                                                           \
} while (0)

    constexpr int NW = SEQ / 16;
    for (int w = 0; w < NW; ++w) {
        GRU_STEP(0,  (DIR ? 15 : 0));
        GRU_STEP(1,  (DIR ? 14 : 1));
        GRU_STEP(2,  (DIR ? 13 : 2));
        GRU_STEP(3,  (DIR ? 12 : 3));
        GRU_STEP(4,  (DIR ? 11 : 4));
        GRU_STEP(5,  (DIR ? 10 : 5));
        GRU_STEP(6,  (DIR ? 9  : 6));
        GRU_STEP(7,  (DIR ? 8  : 7));
        GRU_STEP(8,  (DIR ? 7  : 8));
        GRU_STEP(9,  (DIR ? 6  : 9));
        GRU_STEP(10, (DIR ? 5  : 10));
        GRU_STEP(11, (DIR ? 4  : 11));
        GRU_STEP(12, (DIR ? 3  : 12));
        GRU_STEP(13, (DIR ? 2  : 13));
        GRU_STEP(14, (DIR ? 1  : 14));
        GRU_STEP(15, (DIR ? 0  : 15));

        // window-end writeback (half==0 lanes: this unit's 16 timesteps)
        if (half == 0) {
            const int t0 = DIR ? (SEQ - 1 - 16 * w) : 16 * w;
            const int ti = DIR ? -1 : 1;
            outs[(size_t)(t0 + 0  * ti) * HID + u] = hs0;
            outs[(size_t)(t0 + 1  * ti) * HID + u] = hs1;
            outs[(size_t)(t0 + 2  * ti) * HID + u] = hs2;
            outs[(size_t)(t0 + 3  * ti) * HID + u] = hs3;
            outs[(size_t)(t0 + 4  * ti) * HID + u] = hs4;
            outs[(size_t)(t0 + 5  * ti) * HID + u] = hs5;
            outs[(size_t)(t0 + 6  * ti) * HID + u] = hs6;
            outs[(size_t)(t0 + 7  * ti) * HID + u] = hs7;
            outs[(size_t)(t0 + 8  * ti) * HID + u] = hs8;
            outs[(size_t)(t0 + 9  * ti) * HID + u] = hs9;
            outs[(size_t)(t0 + 10 * ti) * HID + u] = hs10;
            outs[(size_t)(t0 + 11 * ti) * HID + u] = hs11;
            outs[(size_t)(t0 + 12 * ti) * HID + u] = hs12;
            outs[(size_t)(t0 + 13 * ti) * HID + u] = hs13;
            outs[(size_t)(t0 + 14 * ti) * HID + u] = hs14;
            outs[(size_t)(t0 + 15 * ti) * HID + u] = hs15;
        }
        // next-window gi (drained at next window's first barrier)
        if (w + 1 < NW) {
            const int bt = DIR ? (SEQ - 16 - 16 * (w + 1)) : (16 * (w + 1));
#pragma unroll
            for (int s = 0; s < 4; ++s) {
                gcu[s][0] = grb[bt + 4 * s + kq];
                gcu[s][1] = gzb[bt + 4 * s + kq];
                gcu[s][2] = gnb[bt + 4 * s + kq];
            }
        }
    }
#undef GRU_STEP
#undef PKQ
}

__global__ __launch_bounds__(256)
__attribute__((amdgpu_waves_per_eu(1, 1)))
void k_recur(
    const uint32_t* __restrict__ gi_ft, const uint32_t* __restrict__ gi_bt,
    const float* __restrict__ Wf_hh, const float* __restrict__ bf_hh,
    const float* __restrict__ Wb_hh, const float* __restrict__ bb_hh,
    const float* __restrict__ h0,
    float* __restrict__ fwd, float* __restrict__ bwd)
{
    if (blockIdx.x == 0) gru_run<0>(gi_ft, Wf_hh, bf_hh, h0, fwd);
    else                 gru_run<1>(gi_bt, Wb_hh, bb_hh, h0, bwd);
}

// ---------------------------------------------------------------------------
// Kernel 3a: logits + softmax, PARALLEL over t (R10-verified, unchanged)
// ---------------------------------------------------------------------------
__global__ __launch_bounds__(256) void k_logits(
    const float* __restrict__ fwd, const float* __restrict__ bwd,
    const float* __restrict__ W_out, const float* __restrict__ b_out,
    float* __restrict__ probs)
{
    __shared__ __align__(16) float4 Wl[NS][64];
    __shared__ float bl[NS];

    const int tid = threadIdx.x;
    for (int i = tid; i < NS * 64; i += 256)
        Wl[i >> 6][i & 63] = ((const float4*)W_out)[i];
    if (tid < NS) bl[tid] = b_out[tid];
    __syncthreads();

    const int t = blockIdx.x * 256 + tid;
    const float4* f4 = (const float4*)(fwd + (size_t)t * HID);
    const float4* b4 = (const float4*)(bwd + (size_t)t * HID);
    float lg[NS];
#pragma unroll
    for (int s = 0; s < NS; ++s) lg[s] = bl[s];
#pragma unroll 4
    for (int k4 = 0; k4 < 32; ++k4) {
        const float4 fv = f4[k4];
        const float4 bv = b4[k4];
#pragma unroll
        for (int s = 0; s < NS; ++s) {
            const float4 wf = Wl[s][k4];
            const float4 wb = Wl[s][k4 + 32];
            lg[s] += wf.x * fv.x + wf.y * fv.y + wf.z * fv.z + wf.w * fv.w
                   + wb.x * bv.x + wb.y * bv.y + wb.z * bv.z + wb.w * bv.w;
        }
    }
    float m = lg[0];
#pragma unroll
    for (int s = 1; s < NS; ++s) m = fmaxf(m, lg[s]);
    float sum = 0.f;
#pragma unroll
    for (int s = 0; s < NS; ++s) { lg[s] = __expf(lg[s] - m); sum += lg[s]; }
    const float inv = 1.f / sum;
    float* po = probs + (size_t)t * NS;
    *(float2*)(po)     = float2{lg[0] * inv, lg[1] * inv};
    *(float2*)(po + 2) = float2{lg[2] * inv, lg[3] * inv};
    *(float2*)(po + 4) = float2{lg[4] * inv, lg[5] * inv};
}

// ---------------------------------------------------------------------------
// Kernel 3b: PARALLEL Viterbi via (max,+) segmented scan (R10-verified)
// ---------------------------------------------------------------------------
__global__ __launch_bounds__(G3) void k_viterbi(
    const float* __restrict__ probs, const float* __restrict__ trans,
    float* __restrict__ out)
{
    __shared__ float p_lds[SEQ * NS];
    __shared__ uint32_t bp32[SEQ - 1];
    __shared__ float Pmat[32][NS][NS];
    __shared__ float vstart[32][NS];
    __shared__ unsigned char cmap[32 * NS];
    __shared__ int bstate[32];
    __shared__ int s_last;

    const int tid = threadIdx.x;

    {
        const float4* src = (const float4*)probs;
        float4* dst = (float4*)p_lds;
#pragma unroll
        for (int r = 0; r < 8; ++r) dst[tid + r * G3] = src[tid + r * G3];
    }
    __syncthreads();

    if (tid < 32 * NS) {
        const int c = tid / NS, i = tid % NS;
        float tc[NS][NS];
#pragma unroll
        for (int k = 0; k < NS; ++k)
#pragma unroll
            for (int j = 0; j < NS; ++j) tc[k][j] = trans[k * NS + j];
        float R[NS];
#pragma unroll
        for (int j = 0; j < NS; ++j) R[j] = (j == i) ? 0.f : -3.0e38f;
        const int lo = 64 * c;
        const int hi = (c == 31) ? (SEQ - 1) : 64 * (c + 1);
        for (int tau = lo + 1; tau <= hi; ++tau) {
            const float2 p01 = *(const float2*)&p_lds[tau * NS];
            const float2 p23 = *(const float2*)&p_lds[tau * NS + 2];
            const float2 p45 = *(const float2*)&p_lds[tau * NS + 4];
            const float pj[NS] = {p01.x, p01.y, p23.x, p23.y, p45.x, p45.y};
            float Rn[NS];
#pragma unroll
            for (int j = 0; j < NS; ++j) {
                float mx = R[0] + tc[0][j];
                mx = fmaxf(mx, R[1] + tc[1][j]);
                mx = fmaxf(mx, R[2] + tc[2][j]);
                mx = fmaxf(mx, R[3] + tc[3][j]);
                mx = fmaxf(mx, R[4] + tc[4][j]);
                mx = fmaxf(mx, R[5] + tc[5][j]);
                Rn[j] = mx + pj[j];
            }
#pragma unroll
            for (int j = 0; j < NS; ++j) R[j] = Rn[j];
        }
#pragma unroll
        for (int j = 0; j < NS; ++j) Pmat[c][i][j] = R[j];
    }
    __syncthreads();

    if (tid == 0) {
        float v[NS];
#pragma unroll
        for (int j = 0; j < NS; ++j) { v[j] = p_lds[j]; vstart[0][j] = v[j]; }
        for (int c = 0; c < 31; ++c) {
            float vn[NS];
#pragma unroll
            for (int j = 0; j < NS; ++j) {
                float mx = v[0] + Pmat[c][0][j];
                mx = fmaxf(mx, v[1] + Pmat[c][1][j]);
                mx = fmaxf(mx, v[2] + Pmat[c][2][j]);
                mx = fmaxf(mx, v[3] + Pmat[c][3][j]);
                mx = fmaxf(mx, v[4] + Pmat[c][4][j]);
                mx = fmaxf(mx, v[5] + Pmat[c][5][j]);
                vn[j] = mx;
            }
#pragma unroll
            for (int j = 0; j < NS; ++j) { v[j] = vn[j]; vstart[c + 1][j] = vn[j]; }
        }
    }
    __syncthreads();

    if (tid < 32) {
        const int c = tid;
        float tc[NS][NS];
#pragma unroll
        for (int k = 0; k < NS; ++k)
#pragma unroll
            for (int j = 0; j < NS; ++j) tc[k][j] = trans[k * NS + j];
        float v[NS];
#pragma unroll
        for (int j = 0; j < NS; ++j) v[j] = vstart[c][j];
        const int lo = 64 * c;
        const int hi = (c == 31) ? (SEQ - 1) : 64 * (c + 1);
        for (int tau = lo + 1; tau <= hi; ++tau) {
            const float2 p01 = *(const float2*)&p_lds[tau * NS];
            const float2 p23 = *(const float2*)&p_lds[tau * NS + 2];
            const float2 p45 = *(const float2*)&p_lds[tau * NS + 4];
            const float pj[NS] = {p01.x, p01.y, p23.x, p23.y, p45.x, p45.y};
            uint32_t bpw = 0;
            float vn[NS];
#pragma unroll
            for (int j = 0; j < NS; ++j) {
                const float c0 = v[0] + tc[0][j];
                const float c1 = v[1] + tc[1][j];
                const float c2 = v[2] + tc[2][j];
                const float c3 = v[3] + tc[3][j];
                const float c4 = v[4] + tc[4][j];
                const float c5 = v[5] + tc[5][j];
                const float best = fmaxf(fmaxf(fmaxf(c0, c1), c2),
                                         fmaxf(fmaxf(c3, c4), c5));
                int bi = 5;
                bi = (c4 == best) ? 4 : bi;
                bi = (c3 == best) ? 3 : bi;
                bi = (c2 == best) ? 2 : bi;
                bi = (c1 == best) ? 1 : bi;
                bi = (c0 == best) ? 0 : bi;
                bpw |= ((uint32_t)bi) << (3 * j);
                vn[j] = pj[j] + best;
            }
            bp32[tau - 1] = bpw;
#pragma unroll
            for (int j = 0; j < NS; ++j) v[j] = vn[j];
        }
        if (c == 31) {
            const float best = fmaxf(fmaxf(fmaxf(v[0], v[1]), v[2]),
                                     fmaxf(fmaxf(v[3], v[4]), v[5]));
            int bi = 5;
            bi = (v[4] == best) ? 4 : bi;
            bi = (v[3] == best) ? 3 : bi;
            bi = (v[2] == best) ? 2 : bi;
            bi = (v[1] == best) ? 1 : bi;
            bi = (v[0] == best) ? 0 : bi;
            out[0] = best; s_last = bi;
        }
    }
    __syncthreads();

    if (tid < 32 * NS) {
        const int c = tid / NS, s0 = tid % NS;
        const int hi = (c == 31) ? (SEQ - 1) : 64 * (c + 1);
        const int lo = 64 * c;
        int s = s0;
        for (int tau = hi; tau > lo; --tau)
            s = (bp32[tau - 1] >> (3 * s)) & 7;
        cmap[c * NS + s0] = (unsigned char)s;
    }
    __syncthreads();

    if (tid == 0) {
        int s = s_last;
        for (int c = 31; c >= 0; --c) {
            s = cmap[c * NS + s];
            bstate[c] = s;
        }
    }
    __syncthreads();

    if (tid < 32) {
        const int c = tid;
        const int hi = (c == 31) ? (SEQ - 1) : 64 * (c + 1);
        const int lo = 64 * c;
        int s = (c == 31) ? s_last : bstate[c + 1];
        for (int tau = hi; tau > lo; --tau) {
            out[1 + tau] = (float)s;
            s = (bp32[tau - 1] >> (3 * s)) & 7;
        }
        if (c == 0) out[1] = (float)s;   // time 0
    }
}

// ---------------------------------------------------------------------------
extern "C" void kernel_launch(void* const* d_in, const int* in_sizes, int n_in,
                              void* d_out, int out_size, void* d_ws, size_t ws_size,
                              hipStream_t stream)
{
    (void)in_sizes; (void)n_in; (void)out_size; (void)ws_size;

    const int*   sent  = (const int*)  d_in[0];
    const float* emb   = (const float*)d_in[1];
    const float* h0    = (const float*)d_in[2];
    const float* Wf_ih = (const float*)d_in[3];
    const float* Wf_hh = (const float*)d_in[4];
    const float* bf_ih = (const float*)d_in[5];
    const float* bf_hh = (const float*)d_in[6];
    const float* Wb_ih = (const float*)d_in[7];
    const float* Wb_hh = (const float*)d_in[8];
    const float* bb_ih = (const float*)d_in[9];
    const float* bb_hh = (const float*)d_in[10];
    const float* W_out = (const float*)d_in[11];
    const float* b_out = (const float*)d_in[12];
    const float* trans = (const float*)d_in[13];
    float* out = (float*)d_out;

    // workspace layout (floats): gi_ft | gi_bt | fwd | bwd.
    // probs aliases gi_ft (dead after k_recur).
    float*    ws    = (float*)d_ws;
    uint32_t* gi_ft = (uint32_t*)ws;
    uint32_t* gi_bt = gi_ft + (size_t)SEQ * 192;
    float*    fwdb  = ws + (size_t)2 * SEQ * G3;
    float*    bwdb  = fwdb + (size_t)SEQ * HID;
    float*    probs = ws;                     // alias of gi_ft region

    k_input_proj<<<SEQ / 16, G3, 0, stream>>>(sent, emb, Wf_ih, bf_ih, Wb_ih, bb_ih, gi_ft, gi_bt);
    k_recur<<<2, 256, 0, stream>>>(gi_ft, gi_bt, Wf_hh, bf_hh, Wb_hh, bb_hh, h0, fwdb, bwdb);
    k_logits<<<SEQ / 256, 256, 0, stream>>>(fwdb, bwdb, W_out, b_out, probs);
    k_viterbi<<<1, G3, 0, stream>>>(probs, trans, out);
}